// Round 1
// baseline (933.317 us; speedup 1.0000x reference)
//
#include <hip/hip_runtime.h>
#include <math.h>

#ifndef LB
#define LB __launch_bounds__(256)
#endif

// ---------------- kernels ----------------

__global__ LB void degree_kernel(const int* __restrict__ row, int E, int* __restrict__ cnt) {
    int i = blockIdx.x * blockDim.x + threadIdx.x;
    int stride = gridDim.x * blockDim.x;
    for (int e = i; e < E; e += stride) atomicAdd(&cnt[row[e]], 1);
}

__global__ LB void inv_kernel(const int* __restrict__ cnt, float* __restrict__ inv, int n) {
    int v = blockIdx.x * blockDim.x + threadIdx.x;
    if (v < n) {
        int c = cnt[v];
        inv[v] = (c > 0) ? (1.0f / (float)c) : 0.0f;
    }
}

// t[v][f] = sum_k h[v][k] * W[f][k];  res[v][f] = lrelu(t + b[f]);  agg zeroed
template <int FIN, int FOUT>
__global__ LB void transform_kernel(const float* __restrict__ h, const float* __restrict__ W,
                                    const float* __restrict__ b, float* __restrict__ t,
                                    float* __restrict__ res, float* __restrict__ agg, int n) {
    int i = blockIdx.x * blockDim.x + threadIdx.x;
    if (i >= n * FOUT) return;
    int v = i / FOUT;
    int f = i % FOUT;
    float s = 0.0f;
#pragma unroll
    for (int k = 0; k < FIN; ++k) s = fmaf(h[v * FIN + k], W[f * FIN + k], s);
    t[i] = s;
    float r = s + b[f];
    res[i] = (r > 0.0f) ? r : 0.01f * r;
    agg[i] = 0.0f;
}

// per (edge, f): atomicAdd(agg[row][f], lrelu(w*t[col][f] + b[f]))
template <int FOUT>
__global__ LB void edge_kernel(const int* __restrict__ row, const int* __restrict__ col,
                               const float* __restrict__ w, const float* __restrict__ t,
                               const float* __restrict__ b, float* __restrict__ agg, int E) {
    int tid = blockIdx.x * blockDim.x + threadIdx.x;
    int f = tid % FOUT;                       // FOUT is power of 2 -> cheap
    int e = tid / FOUT;
    int estride = (gridDim.x * blockDim.x) / FOUT;  // blockDim*gridDim multiple of FOUT
    float bf = b[f];
    for (; e < E; e += estride) {
        int c = col[e];
        float m = fmaf(w[e], t[c * FOUT + f], bf);
        m = (m > 0.0f) ? m : 0.01f * m;
        atomicAdd(&agg[row[e] * FOUT + f], m);
    }
}

// h_next (in place on agg) = agg * inv_cnt[v] + res
template <int FOUT>
__global__ LB void finalize_kernel(float* __restrict__ agg, const float* __restrict__ res,
                                   const float* __restrict__ inv, int n) {
    int i = blockIdx.x * blockDim.x + threadIdx.x;
    if (i < n * FOUT) agg[i] = agg[i] * inv[i / FOUT] + res[i];
}

// partial mean-pool over nodes: 32 features
__global__ LB void pool_kernel(const float* __restrict__ h, float* __restrict__ pool, int n) {
    __shared__ float ls[256];
    int f = threadIdx.x & 31;
    int grp = threadIdx.x >> 5;                 // 8 groups per block
    int gid = blockIdx.x * (blockDim.x >> 5) + grp;
    int ngrp = (blockDim.x >> 5) * gridDim.x;
    float s = 0.0f;
    for (int v = gid; v < n; v += ngrp) s += h[v * 32 + f];
    ls[threadIdx.x] = s;
    __syncthreads();
    if (threadIdx.x < 32) {
        float tot = 0.0f;
#pragma unroll
        for (int g = 0; g < 8; ++g) tot += ls[g * 32 + threadIdx.x];
        atomicAdd(&pool[threadIdx.x], tot);
    }
}

__global__ void head_kernel(const float* __restrict__ pool, const float* __restrict__ W7,
                            const float* __restrict__ b7, float* __restrict__ out, int n) {
    if (threadIdx.x != 0 || blockIdx.x != 0) return;
    float invn = 1.0f / (float)n;
    float l0 = b7[0], l1 = b7[1];
    for (int f = 0; f < 32; ++f) {
        float p = pool[f] * invn;
        l0 = fmaf(p, W7[f], l0);
        l1 = fmaf(p, W7[32 + f], l1);
    }
    float m = fmaxf(l0, l1);
    float lse = m + logf(expf(l0 - m) + expf(l1 - m));
    out[0] = l0 - lse;
    out[1] = l1 - lse;
}

// ---------------- launch ----------------

extern "C" void kernel_launch(void* const* d_in, const int* in_sizes, int n_in,
                              void* d_out, int out_size, void* d_ws, size_t ws_size,
                              hipStream_t stream) {
    const float* x  = (const float*)d_in[0];   // [N,4]
    const int* edge = (const int*)d_in[1];     // [2,E] (harness converts int64 -> int32)
    const float* w  = (const float*)d_in[2];   // [E]
    const float* W1 = (const float*)d_in[3];   // [8,4]
    const float* b1 = (const float*)d_in[4];
    const float* W3 = (const float*)d_in[5];   // [16,8]
    const float* b3 = (const float*)d_in[6];
    const float* W5 = (const float*)d_in[7];   // [32,16]
    const float* b5 = (const float*)d_in[8];
    const float* W7 = (const float*)d_in[9];   // [2,32]
    const float* b7 = (const float*)d_in[10];
    float* out = (float*)d_out;

    const int N = in_sizes[0] / 4;
    const int E = in_sizes[1] / 2;
    const int* row = edge;
    const int* col = edge + E;

    // workspace layout (all 256B-aligned)
    char* ws = (char*)d_ws;
    size_t off = 0;
    auto alloc = [&](size_t bytes) {
        void* p = ws + off;
        off += (bytes + 255) & ~(size_t)255;
        return p;
    };
    int*   cnt  = (int*)alloc((size_t)N * 4);
    float* inv  = (float*)alloc((size_t)N * 4);
    float* pool = (float*)alloc(32 * 4);
    float* t    = (float*)alloc((size_t)N * 32 * 4);
    float* res  = (float*)alloc((size_t)N * 32 * 4);
    float* aggA = (float*)alloc((size_t)N * 32 * 4);
    float* aggB = (float*)alloc((size_t)N * 32 * 4);
    (void)ws_size;

    hipMemsetAsync(cnt, 0, (size_t)N * 4, stream);
    hipMemsetAsync(pool, 0, 32 * 4, stream);

    const int B = 256;
    degree_kernel<<<2048, B, 0, stream>>>(row, E, cnt);
    inv_kernel<<<(N + B - 1) / B, B, 0, stream>>>(cnt, inv, N);

    // ---- block 1: 4 -> 8 ----
    transform_kernel<4, 8><<<(N * 8 + B - 1) / B, B, 0, stream>>>(x, W1, b1, t, res, aggA, N);
    edge_kernel<8><<<4096, B, 0, stream>>>(row, col, w, t, b1, aggA, E);
    finalize_kernel<8><<<(N * 8 + B - 1) / B, B, 0, stream>>>(aggA, res, inv, N);

    // ---- block 2: 8 -> 16 ----
    transform_kernel<8, 16><<<(N * 16 + B - 1) / B, B, 0, stream>>>(aggA, W3, b3, t, res, aggB, N);
    edge_kernel<16><<<4096, B, 0, stream>>>(row, col, w, t, b3, aggB, E);
    finalize_kernel<16><<<(N * 16 + B - 1) / B, B, 0, stream>>>(aggB, res, inv, N);

    // ---- block 3: 16 -> 32 ----
    transform_kernel<16, 32><<<(N * 32 + B - 1) / B, B, 0, stream>>>(aggB, W5, b5, t, res, aggA, N);
    edge_kernel<32><<<4096, B, 0, stream>>>(row, col, w, t, b5, aggA, E);
    finalize_kernel<32><<<(N * 32 + B - 1) / B, B, 0, stream>>>(aggA, res, inv, N);

    // ---- head ----
    pool_kernel<<<256, B, 0, stream>>>(aggA, pool, N);
    head_kernel<<<1, 64, 0, stream>>>(pool, W7, b7, out, N);
}

// Round 2
// 752.121 us; speedup vs baseline: 1.2409x; 1.2409x over previous
//
#include <hip/hip_runtime.h>
#include <math.h>

#ifndef LB
#define LB __launch_bounds__(256)
#endif

#define SCAN_CHUNK 2048  // per block of 256 threads (8 elems/thread); supports N <= 64*2048

// ---------------- degree + scan + scatter (CSR build) ----------------

__global__ LB void degree_kernel(const int* __restrict__ row, int E, int* __restrict__ cnt) {
    int i = blockIdx.x * blockDim.x + threadIdx.x;
    int stride = gridDim.x * blockDim.x;
    for (int e = i; e < E; e += stride) atomicAdd(&cnt[row[e]], 1);
}

__global__ LB void scan_sum_kernel(const int* __restrict__ cnt, int n, int* __restrict__ blocksum) {
    int base = blockIdx.x * SCAN_CHUNK;
    int sum = 0;
    for (int i = threadIdx.x; i < SCAN_CHUNK; i += 256) {
        int idx = base + i;
        sum += (idx < n) ? cnt[idx] : 0;
    }
#pragma unroll
    for (int o = 32; o; o >>= 1) sum += __shfl_down(sum, o);
    __shared__ int ws[4];
    if ((threadIdx.x & 63) == 0) ws[threadIdx.x >> 6] = sum;
    __syncthreads();
    if (threadIdx.x == 0) blocksum[blockIdx.x] = ws[0] + ws[1] + ws[2] + ws[3];
}

// single block, 64 threads; nb <= 64
__global__ void scan_offsets_kernel(const int* __restrict__ blocksum, int nb,
                                    int* __restrict__ blockoff) {
    int lane = threadIdx.x;
    int v = (lane < nb) ? blocksum[lane] : 0;
    int orig = v;
#pragma unroll
    for (int o = 1; o < 64; o <<= 1) {
        int u = __shfl_up(v, o);
        if (lane >= o) v += u;
    }
    if (lane < nb) blockoff[lane] = v - orig;  // exclusive
}

__global__ LB void scan_scatter_kernel(const int* __restrict__ cnt, int n,
                                       const int* __restrict__ blockoff,
                                       int* __restrict__ rowptr, int* __restrict__ wr, int E) {
    int base = blockIdx.x * SCAN_CHUNK;
    int idx0 = base + threadIdx.x * 8;
    int vals[8];
    int s = 0;
#pragma unroll
    for (int k = 0; k < 8; ++k) {
        int id = idx0 + k;
        vals[k] = (id < n) ? cnt[id] : 0;
        s += vals[k];
    }
    int lane = threadIdx.x & 63, wid = threadIdx.x >> 6;
    int inc = s;
#pragma unroll
    for (int o = 1; o < 64; o <<= 1) {
        int u = __shfl_up(inc, o);
        if (lane >= o) inc += u;
    }
    __shared__ int wsum[4];
    if (lane == 63) wsum[wid] = inc;
    __syncthreads();
    int woff = 0;
    for (int i = 0; i < wid; ++i) woff += wsum[i];
    int excl = inc - s + woff + blockoff[blockIdx.x];
#pragma unroll
    for (int k = 0; k < 8; ++k) {
        int id = idx0 + k;
        if (id < n) { rowptr[id] = excl; wr[id] = excl; }
        excl += vals[k];
    }
    if (blockIdx.x == 0 && threadIdx.x == 0) rowptr[n] = E;
}

// pack (col, w) as float2 into CSR edge order
__global__ LB void scatter_kernel(const int* __restrict__ row, const int* __restrict__ col,
                                  const float* __restrict__ w, int* __restrict__ wr,
                                  float2* __restrict__ csr, int E) {
    int i = blockIdx.x * blockDim.x + threadIdx.x;
    int stride = gridDim.x * blockDim.x;
    for (int e = i; e < E; e += stride) {
        int r = row[e];
        int pos = atomicAdd(&wr[r], 1);
        csr[pos] = make_float2(__int_as_float(col[e]), w[e]);
    }
}

// ---------------- per-layer kernels ----------------

// t[v][f] = sum_k h[v][k] * W[f][k]
template <int FIN, int FOUT>
__global__ LB void transform_kernel(const float* __restrict__ h, const float* __restrict__ W,
                                    float* __restrict__ t, int n) {
    int i = blockIdx.x * blockDim.x + threadIdx.x;
    if (i >= n * FOUT) return;
    int v = i / FOUT;
    int f = i % FOUT;
    float s = 0.0f;
#pragma unroll
    for (int k = 0; k < FIN; ++k) s = fmaf(h[v * FIN + k], W[f * FIN + k], s);
    t[i] = s;
}

// gather-side aggregation + fused residual/finalize:
// h[v][f] = inv_deg * sum_{e in row v} lrelu(w_e * t[col_e][f] + b[f]) + lrelu(t[v][f] + b[f])
template <int F>
__global__ LB void agg_kernel(const int* __restrict__ rowptr, const float2* __restrict__ csr,
                              const float* __restrict__ t, const float* __restrict__ b,
                              float* __restrict__ h, int n) {
    constexpr int RPB = 256 / F;
    int lane = threadIdx.x % F;
    int grp = threadIdx.x / F;
    int v = blockIdx.x * RPB + grp;
    if (v >= n) return;
    int beg = rowptr[v], end = rowptr[v + 1];
    float bf = b[lane];
    float acc0 = 0.0f, acc1 = 0.0f;
    int j = beg;
    for (; j + 1 < end; j += 2) {
        float2 cw0 = csr[j];
        float2 cw1 = csr[j + 1];
        int c0 = __float_as_int(cw0.x);
        int c1 = __float_as_int(cw1.x);
        float m0 = fmaf(cw0.y, t[c0 * F + lane], bf);
        float m1 = fmaf(cw1.y, t[c1 * F + lane], bf);
        acc0 += (m0 > 0.0f) ? m0 : 0.01f * m0;
        acc1 += (m1 > 0.0f) ? m1 : 0.01f * m1;
    }
    if (j < end) {
        float2 cw = csr[j];
        int c = __float_as_int(cw.x);
        float m = fmaf(cw.y, t[c * F + lane], bf);
        acc0 += (m > 0.0f) ? m : 0.01f * m;
    }
    int deg = end - beg;
    float inv = (deg > 0) ? (1.0f / (float)deg) : 0.0f;
    float r = t[v * F + lane] + bf;
    r = (r > 0.0f) ? r : 0.01f * r;
    h[v * F + lane] = (acc0 + acc1) * inv + r;
}

// ---------------- head ----------------

__global__ LB void pool_kernel(const float* __restrict__ h, float* __restrict__ pool, int n) {
    __shared__ float ls[256];
    int f = threadIdx.x & 31;
    int grp = threadIdx.x >> 5;
    int gid = blockIdx.x * (blockDim.x >> 5) + grp;
    int ngrp = (blockDim.x >> 5) * gridDim.x;
    float s = 0.0f;
    for (int v = gid; v < n; v += ngrp) s += h[v * 32 + f];
    ls[threadIdx.x] = s;
    __syncthreads();
    if (threadIdx.x < 32) {
        float tot = 0.0f;
#pragma unroll
        for (int g = 0; g < 8; ++g) tot += ls[g * 32 + threadIdx.x];
        atomicAdd(&pool[threadIdx.x], tot);
    }
}

__global__ void head_kernel(const float* __restrict__ pool, const float* __restrict__ W7,
                            const float* __restrict__ b7, float* __restrict__ out, int n) {
    if (threadIdx.x != 0 || blockIdx.x != 0) return;
    float invn = 1.0f / (float)n;
    float l0 = b7[0], l1 = b7[1];
    for (int f = 0; f < 32; ++f) {
        float p = pool[f] * invn;
        l0 = fmaf(p, W7[f], l0);
        l1 = fmaf(p, W7[32 + f], l1);
    }
    float m = fmaxf(l0, l1);
    float lse = m + logf(expf(l0 - m) + expf(l1 - m));
    out[0] = l0 - lse;
    out[1] = l1 - lse;
}

// ---------------- launch ----------------

extern "C" void kernel_launch(void* const* d_in, const int* in_sizes, int n_in,
                              void* d_out, int out_size, void* d_ws, size_t ws_size,
                              hipStream_t stream) {
    const float* x  = (const float*)d_in[0];   // [N,4]
    const int* edge = (const int*)d_in[1];     // [2,E]
    const float* w  = (const float*)d_in[2];   // [E]
    const float* W1 = (const float*)d_in[3];   // [8,4]
    const float* b1 = (const float*)d_in[4];
    const float* W3 = (const float*)d_in[5];   // [16,8]
    const float* b3 = (const float*)d_in[6];
    const float* W5 = (const float*)d_in[7];   // [32,16]
    const float* b5 = (const float*)d_in[8];
    const float* W7 = (const float*)d_in[9];   // [2,32]
    const float* b7 = (const float*)d_in[10];
    float* out = (float*)d_out;

    const int N = in_sizes[0] / 4;
    const int E = in_sizes[1] / 2;
    const int* row = edge;
    const int* col = edge + E;

    char* ws = (char*)d_ws;
    size_t off = 0;
    auto alloc = [&](size_t bytes) {
        void* p = ws + off;
        off += (bytes + 255) & ~(size_t)255;
        return p;
    };
    int*    cnt      = (int*)alloc((size_t)N * 4);
    int*    rowptr   = (int*)alloc(((size_t)N + 1) * 4);
    int*    wr       = (int*)alloc((size_t)N * 4);
    int*    blocksum = (int*)alloc(256 * 4);
    int*    blockoff = (int*)alloc(256 * 4);
    float*  pool     = (float*)alloc(32 * 4);
    float*  t        = (float*)alloc((size_t)N * 32 * 4);
    float*  h        = (float*)alloc((size_t)N * 32 * 4);
    float2* csr      = (float2*)alloc((size_t)E * 8);
    (void)ws_size;

    hipMemsetAsync(cnt, 0, (size_t)N * 4, stream);
    hipMemsetAsync(pool, 0, 32 * 4, stream);

    const int B = 256;
    const int nb = (N + SCAN_CHUNK - 1) / SCAN_CHUNK;  // <= 64 for N <= 131072

    // CSR build
    degree_kernel<<<4096, B, 0, stream>>>(row, E, cnt);
    scan_sum_kernel<<<nb, B, 0, stream>>>(cnt, N, blocksum);
    scan_offsets_kernel<<<1, 64, 0, stream>>>(blocksum, nb, blockoff);
    scan_scatter_kernel<<<nb, B, 0, stream>>>(cnt, N, blockoff, rowptr, wr, E);
    scatter_kernel<<<4096, B, 0, stream>>>(row, col, w, wr, csr, E);

    // ---- block 1: 4 -> 8 ----
    transform_kernel<4, 8><<<(N * 8 + B - 1) / B, B, 0, stream>>>(x, W1, t, N);
    agg_kernel<8><<<(N + 31) / 32, B, 0, stream>>>(rowptr, csr, t, b1, h, N);

    // ---- block 2: 8 -> 16 ----
    transform_kernel<8, 16><<<(N * 16 + B - 1) / B, B, 0, stream>>>(h, W3, t, N);
    agg_kernel<16><<<(N + 15) / 16, B, 0, stream>>>(rowptr, csr, t, b3, h, N);

    // ---- block 3: 16 -> 32 ----
    transform_kernel<16, 32><<<(N * 32 + B - 1) / B, B, 0, stream>>>(h, W5, t, N);
    agg_kernel<32><<<(N + 7) / 8, B, 0, stream>>>(rowptr, csr, t, b5, h, N);

    // ---- head ----
    pool_kernel<<<256, B, 0, stream>>>(h, pool, N);
    head_kernel<<<1, 64, 0, stream>>>(pool, W7, b7, out, N);
}